// Round 2
// baseline (301.237 us; speedup 1.0000x reference)
//
#include <hip/hip_runtime.h>
#include <stdint.h>

#define HH 128
#define WW 128
#define CIN 256
#define OCH 256
#define HW (HH*WW)

typedef __attribute__((ext_vector_type(8))) short bf16x8;
typedef __attribute__((ext_vector_type(16))) float f32x16;

static __device__ __forceinline__ uint16_t f2bf(float f) {
  uint32_t u = __builtin_bit_cast(uint32_t, f);
  u += 0x7FFFu + ((u >> 16) & 1u);
  return (uint16_t)(u >> 16);
}
static __device__ __forceinline__ float bf2f(uint16_t h) {
  uint32_t u = ((uint32_t)h) << 16;
  return __builtin_bit_cast(float, u);
}

// lgkm-only barrier: LDS visibility without draining in-flight global loads
#define LBAR() asm volatile("s_waitcnt lgkmcnt(0)\ns_barrier" ::: "memory")

// ---------------- pack w -> bf16 [k][c8][oc][8] ----------------
__global__ void pack_w_kernel(const float* __restrict__ w, uint16_t* __restrict__ wpk) {
  int i = blockIdx.x * 256 + threadIdx.x;      // < 9*32*256*8 = 589824
  int ci = i & 7;
  int oc = (i >> 3) & 255;
  int c8 = (i >> 11) & 31;
  int k  = i >> 16;
  int c = c8 * 8 + ci;
  wpk[i] = f2bf(w[(oc * 256 + c) * 9 + k]);
}

// ---------------- x NCHW f32 -> NHWC bf16 ----------------
__global__ void transpose_kernel(const float* __restrict__ x, uint32_t* __restrict__ xt) {
  __shared__ float tile[64][65];
  int wg = blockIdx.x;            // 2048
  int b  = wg >> 10;
  int r  = wg & 1023;
  int pt = r >> 2, ct = r & 3;
  int p0 = pt * 64, c0 = ct * 64;
  int t = threadIdx.x;
  int px4 = (t & 15) * 4;
#pragma unroll
  for (int i = 0; i < 4; ++i) {
    int cl = i * 16 + (t >> 4);
    const float4 v = *(const float4*)&x[(size_t)(b * CIN + c0 + cl) * HW + p0 + px4];
    tile[cl][px4 + 0] = v.x; tile[cl][px4 + 1] = v.y;
    tile[cl][px4 + 2] = v.z; tile[cl][px4 + 3] = v.w;
  }
  __syncthreads();
  int c2 = t & 31, pr = t >> 5;
#pragma unroll
  for (int i = 0; i < 8; ++i) {
    int pl = i * 8 + pr;
    uint32_t lo = f2bf(tile[2 * c2][pl]);
    uint32_t hi = f2bf(tile[2 * c2 + 1][pl]);
    xt[(size_t)(b * HW + p0 + pl) * 128 + (c0 >> 1) + c2] = lo | (hi << 16);
  }
}

// ---------------- offset conv: 512 blocks x 256 thr, 64 px/block, 4-way c-split ----------------
__global__ __launch_bounds__(256) void offc_kernel(const float* __restrict__ off,
                                                   const float* __restrict__ w_off,
                                                   const float* __restrict__ b_off,
                                                   float* __restrict__ offs) {
  __shared__ float wl[27 * 256];
  __shared__ float red[3][64][29];
  int t = threadIdx.x;
  for (int r = t; r < 27 * 256; r += 256) wl[r] = w_off[r];
  int pxl = t & 63, q = t >> 6;
  int px = blockIdx.x * 64 + pxl;
  int b = px >> 14, yx = px & 16383;
  float acc[27];
#pragma unroll
  for (int jj = 0; jj < 27; ++jj) acc[jj] = 0.f;
  const float* op = off + (size_t)b * CIN * HW + yx;
  int cbase = q * 64;
  __syncthreads();
  for (int c = 0; c < 64; c += 4) {
    float v0 = op[(size_t)(cbase + c + 0) * HW];
    float v1 = op[(size_t)(cbase + c + 1) * HW];
    float v2 = op[(size_t)(cbase + c + 2) * HW];
    float v3 = op[(size_t)(cbase + c + 3) * HW];
    const float* wr = wl + cbase + c;
#pragma unroll
    for (int jj = 0; jj < 27; ++jj) {
      acc[jj] = fmaf(wr[jj * 256 + 0], v0, acc[jj]);
      acc[jj] = fmaf(wr[jj * 256 + 1], v1, acc[jj]);
      acc[jj] = fmaf(wr[jj * 256 + 2], v2, acc[jj]);
      acc[jj] = fmaf(wr[jj * 256 + 3], v3, acc[jj]);
    }
  }
  if (q > 0) {
#pragma unroll
    for (int jj = 0; jj < 27; ++jj) red[q - 1][pxl][jj] = acc[jj];
  }
  __syncthreads();
  if (q == 0) {
    float fin[27];
#pragma unroll
    for (int jj = 0; jj < 27; ++jj)
      acc[jj] += b_off[jj] + red[0][pxl][jj] + red[1][pxl][jj] + red[2][pxl][jj];
#pragma unroll
    for (int k = 0; k < 9; ++k) {
      fin[3 * k + 0] = acc[2 * k];
      fin[3 * k + 1] = acc[2 * k + 1];
      fin[3 * k + 2] = 1.f / (1.f + __expf(-acc[18 + k]));
    }
#pragma unroll
    for (int jj = 0; jj < 27; ++jj) red[0][pxl][jj] = fin[jj];
  }
  __syncthreads();
  float* obase = offs + (size_t)blockIdx.x * 64 * 27;
  for (int r = t; r < 64 * 27; r += 256) {
    int p = r / 27, e = r - p * 27;
    obase[r] = red[0][p][e];
  }
}

// ---------------- fused gather + MFMA GEMM: 1024 blocks, 32px x 256oc tiles ----------------
__global__ __launch_bounds__(256, 4) void main_kernel(
    const uint32_t* __restrict__ xt, const float* __restrict__ offs,
    const uint16_t* __restrict__ wpk, const float* __restrict__ bias,
    float* __restrict__ out) {
  __shared__ struct __align__(16) { unsigned char A[2][32 * 512]; float offs_l[32 * 27]; } sm;

  int wg = blockIdx.x;                  // 1024
  wg = (wg & 7) * 128 + (wg >> 3);      // XCD-aware swizzle (1024 % 8 == 0, bijective)
  int b = wg >> 9;
  int tile = wg & 511;
  int y0 = (tile >> 4) * 4, x0 = (tile & 15) * 8;   // 4y x 8x = 32 px

  int tid = threadIdx.x;
  int lane = tid & 63;
  int wv = tid >> 6;                    // oc-group 0..3
  int l31 = lane & 31, g = lane >> 5;

  {
    int base = b * HW + y0 * WW + x0;
    for (int r = tid; r < 32 * 27; r += 256) {
      int pyl = r / 216;                // 216 = 8*27
      int rem = r - pyl * 216;
      sm.offs_l[r] = offs[(size_t)(base + pyl * WW) * 27 + rem];
    }
  }
  f32x16 acc[2] = {};

  const int hw = tid >> 5;              // px-group 0..7
  const int j = tid & 31;               // channel-octet lane
  const uint4* xt4 = (const uint4*)xt;
  const uint4* wp4 = (const uint4*)wpk;
  const int pb = b * HW;
  const uint32_t rswz = (uint32_t)(l31 << 4);
  const int oc0 = wv * 64 + l31;

  // issue: compute bilinear weights + fire the 4 corner loads for sub-px i of tap kk
  auto issue = [&](int kk, int i, float* wt, uint4* q) {
    int px = hw * 4 + i;
    int kh = kk / 3 - 1, kw = kk % 3 - 1;
    float dy = sm.offs_l[px * 27 + kk * 3 + 0];
    float dx = sm.offs_l[px * 27 + kk * 3 + 1];
    float m  = sm.offs_l[px * 27 + kk * 3 + 2];
    float ys = (float)(y0 + (px >> 3) + kh) + dy;
    float xs = (float)(x0 + (px & 7) + kw) + dx;
    float yf = floorf(ys), xf = floorf(xs);
    float wy1 = ys - yf, wx1 = xs - xf;
    float wy0 = 1.f - wy1, wx0 = 1.f - wx1;
    int iy0 = (int)yf, ix0 = (int)xf;
    int iy1 = iy0 + 1, ix1 = ix0 + 1;
    float vy0 = (iy0 >= 0 && iy0 < HH) ? 1.f : 0.f;
    float vy1 = (iy1 >= 0 && iy1 < HH) ? 1.f : 0.f;
    float vx0 = (ix0 >= 0 && ix0 < WW) ? 1.f : 0.f;
    float vx1 = (ix1 >= 0 && ix1 < WW) ? 1.f : 0.f;
    wt[0] = wy0 * wx0 * vy0 * vx0 * m;
    wt[1] = wy0 * wx1 * vy0 * vx1 * m;
    wt[2] = wy1 * wx0 * vy1 * vx0 * m;
    wt[3] = wy1 * wx1 * vy1 * vx1 * m;
    int cy0 = iy0 < 0 ? 0 : (iy0 > HH - 1 ? HH - 1 : iy0);
    int cy1 = iy1 < 0 ? 0 : (iy1 > HH - 1 ? HH - 1 : iy1);
    int cx0 = ix0 < 0 ? 0 : (ix0 > WW - 1 ? WW - 1 : ix0);
    int cx1 = ix1 < 0 ? 0 : (ix1 > WW - 1 ? WW - 1 : ix1);
    q[0] = xt4[(size_t)(pb + cy0 * WW + cx0) * 32 + j];
    q[1] = xt4[(size_t)(pb + cy0 * WW + cx1) * 32 + j];
    q[2] = xt4[(size_t)(pb + cy1 * WW + cx0) * 32 + j];
    q[3] = xt4[(size_t)(pb + cy1 * WW + cx1) * 32 + j];
  };

  // commit: bilinear combine in f32, pack bf16, swizzled LDS write
  auto commit = [&](int i, const float* wt, const uint4* q, int buf) {
    int px = hw * 4 + i;
    uint32_t u0[4] = {q[0].x, q[0].y, q[0].z, q[0].w};
    uint32_t u1[4] = {q[1].x, q[1].y, q[1].z, q[1].w};
    uint32_t u2[4] = {q[2].x, q[2].y, q[2].z, q[2].w};
    uint32_t u3[4] = {q[3].x, q[3].y, q[3].z, q[3].w};
    uint32_t ow[4];
#pragma unroll
    for (int qd = 0; qd < 4; ++qd) {
      float lo = wt[0] * bf2f((uint16_t)u0[qd]) + wt[1] * bf2f((uint16_t)u1[qd])
               + wt[2] * bf2f((uint16_t)u2[qd]) + wt[3] * bf2f((uint16_t)u3[qd]);
      float hi = wt[0] * bf2f((uint16_t)(u0[qd] >> 16)) + wt[1] * bf2f((uint16_t)(u1[qd] >> 16))
               + wt[2] * bf2f((uint16_t)(u2[qd] >> 16)) + wt[3] * bf2f((uint16_t)(u3[qd] >> 16));
      ow[qd] = (uint32_t)f2bf(lo) | ((uint32_t)f2bf(hi) << 16);
    }
    *(uint4*)(&sm.A[buf][px * 512 + ((j * 16) ^ (px << 4))]) =
        make_uint4(ow[0], ow[1], ow[2], ow[3]);
  };

  auto mfma_half = [&](int kk, int h, int buf) {
    __builtin_amdgcn_s_setprio(1);
#pragma unroll
    for (int chunk = 0; chunk < 4; ++chunk) {
#pragma unroll
      for (int cs = 0; cs < 2; ++cs) {
        int ch = h * 4 + chunk;
        int boff = (ch * 64 + cs * 32 + g * 16) ^ rswz;
        uint4 ua = *(const uint4*)(&sm.A[buf][l31 * 512 + boff]);
        int bidx = kk * 8192 + (ch * 4 + cs * 2 + g) * 256;
        uint4 ub0 = wp4[bidx + oc0];
        uint4 ub1 = wp4[bidx + oc0 + 32];
        bf16x8 a  = __builtin_bit_cast(bf16x8, ua);
        bf16x8 b0 = __builtin_bit_cast(bf16x8, ub0);
        bf16x8 b1 = __builtin_bit_cast(bf16x8, ub1);
        acc[0] = __builtin_amdgcn_mfma_f32_32x32x16_bf16(a, b0, acc[0], 0, 0, 0);
        acc[1] = __builtin_amdgcn_mfma_f32_32x32x16_bf16(a, b1, acc[1], 0, 0, 0);
      }
    }
    __builtin_amdgcn_s_setprio(0);
  };

  LBAR();   // offs_l ready

  // prologue: gather tap 0 into buf 0
  {
    float wt0[4], wt1[4];
    uint4 q0[4], q1[4];
#pragma unroll
    for (int ip = 0; ip < 2; ++ip) {
      issue(0, 2 * ip + 0, wt0, q0);
      issue(0, 2 * ip + 1, wt1, q1);
      commit(2 * ip + 0, wt0, q0, 0);
      commit(2 * ip + 1, wt1, q1, 0);
    }
  }

#pragma unroll 1
  for (int k = 0; k < 9; ++k) {
    int buf = k & 1, nbuf = buf ^ 1;
    float wt0[4], wt1[4];
    uint4 q0[4], q1[4];
    if (k < 8) { issue(k + 1, 0, wt0, q0); issue(k + 1, 1, wt1, q1); }
    LBAR();                         // buf[k&1] writes visible; loads stay in flight
    mfma_half(k, 0, buf);
    if (k < 8) {
      commit(0, wt0, q0, nbuf);
      commit(1, wt1, q1, nbuf);
      issue(k + 1, 2, wt0, q0);
      issue(k + 1, 3, wt1, q1);
    }
    mfma_half(k, 1, buf);
    if (k < 8) {
      commit(2, wt0, q0, nbuf);
      commit(3, wt1, q1, nbuf);
    }
  }

  // ---- epilogue: bias + relu, scatter to NCHW out ----
  float bv0 = bias[wv * 64 + l31];
  float bv1 = bias[wv * 64 + 32 + l31];
#pragma unroll
  for (int tn = 0; tn < 2; ++tn) {
    int oc = wv * 64 + tn * 32 + l31;
    float bv = tn ? bv1 : bv0;
#pragma unroll
    for (int r = 0; r < 16; ++r) {
      int row = (r & 3) + 8 * (r >> 2) + 4 * g;   // px 0..31
      int y = y0 + (row >> 3), x = x0 + (row & 7);
      float v = acc[tn][r] + bv;
      out[((size_t)(b * OCH + oc) << 14) + (y << 7) + x] = fmaxf(v, 0.f);
    }
  }
}

extern "C" void kernel_launch(void* const* d_in, const int* in_sizes, int n_in,
                              void* d_out, int out_size, void* d_ws, size_t ws_size,
                              hipStream_t stream) {
  const float* x     = (const float*)d_in[0];
  const float* off   = (const float*)d_in[1];
  const float* w_off = (const float*)d_in[2];
  const float* b_off = (const float*)d_in[3];
  const float* w     = (const float*)d_in[4];
  const float* bias  = (const float*)d_in[5];
  float* out = (float*)d_out;
  char* ws = (char*)d_ws;
  uint32_t* xt   = (uint32_t*)ws;                              // 16 MB  (NHWC bf16)
  float*    offs = (float*)(ws + 16777216);                    // 3.54 MB (px*27)
  uint16_t* wpk  = (uint16_t*)(ws + 16777216 + 3538944);       // 1.18 MB (packed w)

  pack_w_kernel<<<2304, 256, 0, stream>>>(w, wpk);
  transpose_kernel<<<2048, 256, 0, stream>>>(x, xt);
  offc_kernel<<<512, 256, 0, stream>>>(off, w_off, b_off, offs);
  main_kernel<<<1024, 256, 0, stream>>>(xt, offs, wpk, bias, out);
}

// Round 4
// 251.545 us; speedup vs baseline: 1.1975x; 1.1975x over previous
//
#include <hip/hip_runtime.h>
#include <stdint.h>

#define HH 128
#define WW 128
#define CIN 256
#define OCH 256
#define HW (HH*WW)

typedef __attribute__((ext_vector_type(8))) short bf16x8;
typedef __attribute__((ext_vector_type(16))) float f32x16;

static __device__ __forceinline__ uint16_t f2bf(float f) {
  uint32_t u = __builtin_bit_cast(uint32_t, f);
  u += 0x7FFFu + ((u >> 16) & 1u);
  return (uint16_t)(u >> 16);
}
static __device__ __forceinline__ float bf2f(uint16_t h) {
  uint32_t u = ((uint32_t)h) << 16;
  return __builtin_bit_cast(float, u);
}

// lgkm-only barrier: LDS visibility without draining in-flight global loads
#define LBAR() asm volatile("s_waitcnt lgkmcnt(0)\ns_barrier" ::: "memory")

#define TR_BLOCKS 2048
#define PK_BLOCKS 2304
#define OC_BLOCKS 512

// ---------------- merged prep: transpose | pack_w | offset-conv ----------------
__global__ __launch_bounds__(256) void prep_kernel(
    const float* __restrict__ x, uint32_t* __restrict__ xt,
    const float* __restrict__ w, uint16_t* __restrict__ wpk,
    const float* __restrict__ off, const float* __restrict__ w_off,
    const float* __restrict__ b_off, float* __restrict__ offs) {
  __shared__ __align__(16) char smraw[27 * 4 * 68 * 4];   // 29376 B (union)
  int bid = blockIdx.x;
  int t = threadIdx.x;

  if (bid < TR_BLOCKS) {
    // ---- x NCHW f32 -> NHWC bf16 ----
    float (*tile)[65] = reinterpret_cast<float(*)[65]>(smraw);
    int b = bid >> 10;
    int r = bid & 1023;
    int pt = r >> 2, ct = r & 3;
    int p0 = pt * 64, c0 = ct * 64;
    int px4 = (t & 15) * 4;
#pragma unroll
    for (int i = 0; i < 4; ++i) {
      int cl = i * 16 + (t >> 4);
      const float4 v = *(const float4*)&x[(size_t)(b * CIN + c0 + cl) * HW + p0 + px4];
      tile[cl][px4 + 0] = v.x; tile[cl][px4 + 1] = v.y;
      tile[cl][px4 + 2] = v.z; tile[cl][px4 + 3] = v.w;
    }
    __syncthreads();
    int c2 = t & 31, pr = t >> 5;
#pragma unroll
    for (int i = 0; i < 8; ++i) {
      int pl = i * 8 + pr;
      uint32_t lo = f2bf(tile[2 * c2][pl]);
      uint32_t hi = f2bf(tile[2 * c2 + 1][pl]);
      xt[(size_t)(b * HW + p0 + pl) * 128 + (c0 >> 1) + c2] = lo | (hi << 16);
    }
  } else if (bid < TR_BLOCKS + PK_BLOCKS) {
    // ---- pack w -> bf16 [k][c8][oc][8] ----
    int i = (bid - TR_BLOCKS) * 256 + t;     // < 589824
    int ci = i & 7;
    int oc = (i >> 3) & 255;
    int c8 = (i >> 11) & 31;
    int k  = i >> 16;
    int c = c8 * 8 + ci;
    wpk[i] = f2bf(w[(oc * 256 + c) * 9 + k]);
  } else {
    // ---- offset conv: 64 px/block, c split over lane bits [1:0], shfl reduce ----
    float* wl = (float*)smraw;               // [jj*4+cg][68]
    for (int r = t; r < 27 * 256; r += 256) {
      int jj = r >> 8, rest = r & 255, cg = rest >> 6, c = rest & 63;
      wl[(jj * 4 + cg) * 68 + c] = w_off[r];
    }
    __syncthreads();
    int ob = bid - (TR_BLOCKS + PK_BLOCKS);  // 0..511
    int pxl = t >> 2, cg = t & 3;
    int px = ob * 64 + pxl;
    int b = px >> 14, yx = px & 16383;
    const float* op = off + (size_t)b * (CIN * HW) + (size_t)(cg * 64) * HW + yx;
    float acc[27];
#pragma unroll
    for (int jj = 0; jj < 27; ++jj) acc[jj] = 0.f;
    for (int c = 0; c < 64; c += 4) {
      float v0 = op[(size_t)(c + 0) * HW];
      float v1 = op[(size_t)(c + 1) * HW];
      float v2 = op[(size_t)(c + 2) * HW];
      float v3 = op[(size_t)(c + 3) * HW];
#pragma unroll
      for (int jj = 0; jj < 27; ++jj) {
        const float4 ww = *(const float4*)&wl[(jj * 4 + cg) * 68 + c];
        acc[jj] = fmaf(ww.x, v0, acc[jj]);
        acc[jj] = fmaf(ww.y, v1, acc[jj]);
        acc[jj] = fmaf(ww.z, v2, acc[jj]);
        acc[jj] = fmaf(ww.w, v3, acc[jj]);
      }
    }
#pragma unroll
    for (int jj = 0; jj < 27; ++jj) {
      acc[jj] += __shfl_xor(acc[jj], 1, 64);
      acc[jj] += __shfl_xor(acc[jj], 2, 64);
    }
    float fin[27];
#pragma unroll
    for (int kk = 0; kk < 9; ++kk) {
      fin[3 * kk + 0] = acc[2 * kk + 0] + b_off[2 * kk + 0];
      fin[3 * kk + 1] = acc[2 * kk + 1] + b_off[2 * kk + 1];
      float mm = acc[18 + kk] + b_off[18 + kk];
      fin[3 * kk + 2] = 1.f / (1.f + __expf(-mm));
    }
    float* o = offs + (size_t)px * 27;
#pragma unroll
    for (int jj = 0; jj < 27; ++jj)
      if ((jj & 3) == cg) o[jj] = fin[jj];
  }
}

// ---------------- fused gather + MFMA GEMM: 512 blocks x 512 thr, 64px x 256oc ----------------
__global__ __launch_bounds__(512) void main_kernel(
    const uint32_t* __restrict__ xt, const float* __restrict__ offs,
    const uint16_t* __restrict__ wpk, const float* __restrict__ bias,
    float* __restrict__ out) {
  __shared__ struct __align__(16) { unsigned char A[2][64 * 512]; float offs_l[64 * 27]; } sm;

  int wg = blockIdx.x;                  // 512
  wg = (wg & 7) * 64 + (wg >> 3);       // XCD-aware swizzle (512 % 8 == 0, bijective)
  int b = wg >> 8;
  int tile = wg & 255;
  int y0 = (tile >> 3) * 4, x0 = (tile & 7) * 16;   // 4y x 16x = 64 px

  int tid = threadIdx.x;
  int lane = tid & 63;
  int wv = tid >> 6;                    // 0..7
  int ocg = wv & 3, ph = wv >> 2;       // oc-group, px-half
  int l31 = lane & 31, g = lane >> 5;

  {
    int base = b * HW + y0 * WW + x0;
    for (int r = tid; r < 64 * 27; r += 512) {
      int pyl = r / 432;                // 432 = 16*27
      int rem = r - pyl * 432;
      sm.offs_l[r] = offs[(size_t)(base + pyl * WW) * 27 + rem];
    }
  }
  f32x16 acc[2] = {};

  const int pxg = tid >> 5;             // px-group 0..15 (4 px each)
  const int j = tid & 31;               // channel-octet lane
  const uint4* xt4 = (const uint4*)xt;
  const uint4* wp4 = (const uint4*)wpk;
  const int pb = b * HW;
  const uint32_t rswz = (uint32_t)(l31 << 4);
  const int oc0 = ocg * 64 + l31;
  const int arow = (l31 + 32 * ph) * 512;

  auto issue = [&](int kk, int i, float* wt, uint4* q) {
    int px = pxg * 4 + i;
    int kh = kk / 3 - 1, kw = kk % 3 - 1;
    float dy = sm.offs_l[px * 27 + kk * 3 + 0];
    float dx = sm.offs_l[px * 27 + kk * 3 + 1];
    float m  = sm.offs_l[px * 27 + kk * 3 + 2];
    float ys = (float)(y0 + (px >> 4) + kh) + dy;
    float xs = (float)(x0 + (px & 15) + kw) + dx;
    float yf = floorf(ys), xf = floorf(xs);
    float wy1 = ys - yf, wx1 = xs - xf;
    float wy0 = 1.f - wy1, wx0 = 1.f - wx1;
    int iy0 = (int)yf, ix0 = (int)xf;
    int iy1 = iy0 + 1, ix1 = ix0 + 1;
    float vy0 = (iy0 >= 0 && iy0 < HH) ? 1.f : 0.f;
    float vy1 = (iy1 >= 0 && iy1 < HH) ? 1.f : 0.f;
    float vx0 = (ix0 >= 0 && ix0 < WW) ? 1.f : 0.f;
    float vx1 = (ix1 >= 0 && ix1 < WW) ? 1.f : 0.f;
    wt[0] = wy0 * wx0 * vy0 * vx0 * m;
    wt[1] = wy0 * wx1 * vy0 * vx1 * m;
    wt[2] = wy1 * wx0 * vy1 * vx0 * m;
    wt[3] = wy1 * wx1 * vy1 * vx1 * m;
    int cy0 = iy0 < 0 ? 0 : (iy0 > HH - 1 ? HH - 1 : iy0);
    int cy1 = iy1 < 0 ? 0 : (iy1 > HH - 1 ? HH - 1 : iy1);
    int cx0 = ix0 < 0 ? 0 : (ix0 > WW - 1 ? WW - 1 : ix0);
    int cx1 = ix1 < 0 ? 0 : (ix1 > WW - 1 ? WW - 1 : ix1);
    q[0] = xt4[(size_t)(pb + cy0 * WW + cx0) * 32 + j];
    q[1] = xt4[(size_t)(pb + cy0 * WW + cx1) * 32 + j];
    q[2] = xt4[(size_t)(pb + cy1 * WW + cx0) * 32 + j];
    q[3] = xt4[(size_t)(pb + cy1 * WW + cx1) * 32 + j];
  };

  auto commit = [&](int i, const float* wt, const uint4* q, int buf) {
    int px = pxg * 4 + i;
    uint32_t u0[4] = {q[0].x, q[0].y, q[0].z, q[0].w};
    uint32_t u1[4] = {q[1].x, q[1].y, q[1].z, q[1].w};
    uint32_t u2[4] = {q[2].x, q[2].y, q[2].z, q[2].w};
    uint32_t u3[4] = {q[3].x, q[3].y, q[3].z, q[3].w};
    uint32_t ow[4];
#pragma unroll
    for (int qd = 0; qd < 4; ++qd) {
      float lo = wt[0] * bf2f((uint16_t)u0[qd]) + wt[1] * bf2f((uint16_t)u1[qd])
               + wt[2] * bf2f((uint16_t)u2[qd]) + wt[3] * bf2f((uint16_t)u3[qd]);
      float hi = wt[0] * bf2f((uint16_t)(u0[qd] >> 16)) + wt[1] * bf2f((uint16_t)(u1[qd] >> 16))
               + wt[2] * bf2f((uint16_t)(u2[qd] >> 16)) + wt[3] * bf2f((uint16_t)(u3[qd] >> 16));
      ow[qd] = (uint32_t)f2bf(lo) | ((uint32_t)f2bf(hi) << 16);
    }
    *(uint4*)(&sm.A[buf][px * 512 + ((j * 16) ^ ((px & 31) << 4))]) =
        make_uint4(ow[0], ow[1], ow[2], ow[3]);
  };

  auto mfma_half = [&](int kk, int h, int buf) {
    __builtin_amdgcn_s_setprio(1);
#pragma unroll
    for (int chunk = 0; chunk < 4; ++chunk) {
#pragma unroll
      for (int cs = 0; cs < 2; ++cs) {
        int ch = h * 4 + chunk;
        int boff = (ch * 64 + cs * 32 + g * 16) ^ rswz;
        uint4 ua = *(const uint4*)(&sm.A[buf][arow + boff]);
        int bidx = kk * 8192 + (ch * 4 + cs * 2 + g) * 256;
        uint4 ub0 = wp4[bidx + oc0];
        uint4 ub1 = wp4[bidx + oc0 + 32];
        bf16x8 a  = __builtin_bit_cast(bf16x8, ua);
        bf16x8 b0 = __builtin_bit_cast(bf16x8, ub0);
        bf16x8 b1 = __builtin_bit_cast(bf16x8, ub1);
        acc[0] = __builtin_amdgcn_mfma_f32_32x32x16_bf16(a, b0, acc[0], 0, 0, 0);
        acc[1] = __builtin_amdgcn_mfma_f32_32x32x16_bf16(a, b1, acc[1], 0, 0, 0);
      }
    }
    __builtin_amdgcn_s_setprio(0);
  };

  LBAR();   // offs_l ready

  {
    float wt0[4], wt1[4];
    uint4 q0[4], q1[4];
#pragma unroll
    for (int ip = 0; ip < 2; ++ip) {
      issue(0, 2 * ip + 0, wt0, q0);
      issue(0, 2 * ip + 1, wt1, q1);
      commit(2 * ip + 0, wt0, q0, 0);
      commit(2 * ip + 1, wt1, q1, 0);
    }
  }

#pragma unroll 1
  for (int k = 0; k < 9; ++k) {
    int buf = k & 1, nbuf = buf ^ 1;
    float wt0[4], wt1[4];
    uint4 q0[4], q1[4];
    if (k < 8) { issue(k + 1, 0, wt0, q0); issue(k + 1, 1, wt1, q1); }
    LBAR();                         // buf writes visible; global loads stay in flight
    mfma_half(k, 0, buf);
    if (k < 8) {
      commit(0, wt0, q0, nbuf);
      commit(1, wt1, q1, nbuf);
      issue(k + 1, 2, wt0, q0);
      issue(k + 1, 3, wt1, q1);
    }
    mfma_half(k, 1, buf);
    if (k < 8) {
      commit(2, wt0, q0, nbuf);
      commit(3, wt1, q1, nbuf);
    }
  }

  // ---- epilogue: bias + relu, scatter to NCHW out ----
  float bv0 = bias[ocg * 64 + l31];
  float bv1 = bias[ocg * 64 + 32 + l31];
#pragma unroll
  for (int tn = 0; tn < 2; ++tn) {
    int oc = ocg * 64 + tn * 32 + l31;
    float bv = tn ? bv1 : bv0;
#pragma unroll
    for (int r = 0; r < 16; ++r) {
      int row = 32 * ph + (r & 3) + 8 * (r >> 2) + 4 * g;   // px 0..63
      int y = y0 + (row >> 4), x = x0 + (row & 15);
      float v = acc[tn][r] + bv;
      out[((size_t)(b * OCH + oc) << 14) + (y << 7) + x] = fmaxf(v, 0.f);
    }
  }
}

extern "C" void kernel_launch(void* const* d_in, const int* in_sizes, int n_in,
                              void* d_out, int out_size, void* d_ws, size_t ws_size,
                              hipStream_t stream) {
  const float* x     = (const float*)d_in[0];
  const float* off   = (const float*)d_in[1];
  const float* w_off = (const float*)d_in[2];
  const float* b_off = (const float*)d_in[3];
  const float* w     = (const float*)d_in[4];
  const float* bias  = (const float*)d_in[5];
  float* out = (float*)d_out;
  char* ws = (char*)d_ws;
  uint32_t* xt   = (uint32_t*)ws;                              // 16 MB  (NHWC bf16)
  float*    offs = (float*)(ws + 16777216);                    // 3.54 MB (px*27)
  uint16_t* wpk  = (uint16_t*)(ws + 16777216 + 3538944);       // 1.18 MB (packed w)

  prep_kernel<<<TR_BLOCKS + PK_BLOCKS + OC_BLOCKS, 256, 0, stream>>>(
      x, xt, w, wpk, off, w_off, b_off, offs);
  main_kernel<<<512, 512, 0, stream>>>(xt, offs, wpk, bias, out);
}